// Round 1
// baseline (9943.581 us; speedup 1.0000x reference)
//
#include <hip/hip_runtime.h>
#include <math.h>

// Sizes (fixed by the reference)
#define BB  64
#define SS  128
#define HH  1024
#define EE  1024
#define EMBD 512
#define VV  32000
#define TT  50

// ---------------------------------------------------------------------------
// Generic M=64 tiled f32 GEMM tile: C[64 x 64] += A[64 x K] * B
//  BT=true : B stored [N x K] row-major (we compute A @ B^T)
//  BT=false: B stored [K x N] row-major (we compute A @ B)
// Block = 256 threads, tile 64x64, K-chunks of 32.
// ---------------------------------------------------------------------------
template<bool BT>
__device__ __forceinline__ void gemm_tile(const float* __restrict__ A, int lda,
                                          const float* __restrict__ B, int ldb,
                                          float* __restrict__ C, size_t ldc, int K)
{
    __shared__ __attribute__((aligned(16))) float As[32][68];  // [k][m], stride 68 keeps 16B align + spreads banks
    __shared__ __attribute__((aligned(16))) float Bs[32][68];  // [k][n]
    int tid = threadIdx.x;
    int tx = tid & 15, ty = tid >> 4;       // output micro-tile coords
    float acc[4][4] = {};
    int lr = tid >> 2;                      // 0..63  (row for transposed staging)
    int lk = (tid & 3) << 3;                // 0,8,16,24
    int bk = tid >> 3;                      // 0..31  (k for BN staging)
    int bn = (tid & 7) << 3;                // 0..56

    for (int kc = 0; kc < K; kc += 32) {
        float4 a0 = *(const float4*)(A + (size_t)lr * lda + kc + lk);
        float4 a1 = *(const float4*)(A + (size_t)lr * lda + kc + lk + 4);
        As[lk+0][lr] = a0.x; As[lk+1][lr] = a0.y; As[lk+2][lr] = a0.z; As[lk+3][lr] = a0.w;
        As[lk+4][lr] = a1.x; As[lk+5][lr] = a1.y; As[lk+6][lr] = a1.z; As[lk+7][lr] = a1.w;
        if (BT) {
            float4 b0 = *(const float4*)(B + (size_t)lr * ldb + kc + lk);
            float4 b1 = *(const float4*)(B + (size_t)lr * ldb + kc + lk + 4);
            Bs[lk+0][lr] = b0.x; Bs[lk+1][lr] = b0.y; Bs[lk+2][lr] = b0.z; Bs[lk+3][lr] = b0.w;
            Bs[lk+4][lr] = b1.x; Bs[lk+5][lr] = b1.y; Bs[lk+6][lr] = b1.z; Bs[lk+7][lr] = b1.w;
        } else {
            float4 b0 = *(const float4*)(B + (size_t)(kc + bk) * ldb + bn);
            float4 b1 = *(const float4*)(B + (size_t)(kc + bk) * ldb + bn + 4);
            *(float4*)&Bs[bk][bn]     = b0;
            *(float4*)&Bs[bk][bn + 4] = b1;
        }
        __syncthreads();
        #pragma unroll 8
        for (int k = 0; k < 32; ++k) {
            float4 av = *(const float4*)&As[k][ty << 2];
            float4 bv = *(const float4*)&Bs[k][tx << 2];
            float am[4] = {av.x, av.y, av.z, av.w};
            float bm[4] = {bv.x, bv.y, bv.z, bv.w};
            #pragma unroll
            for (int i = 0; i < 4; ++i)
                #pragma unroll
                for (int j = 0; j < 4; ++j)
                    acc[i][j] = fmaf(am[i], bm[j], acc[i][j]);
        }
        __syncthreads();
    }
    #pragma unroll
    for (int i = 0; i < 4; ++i) {
        float4 w = make_float4(acc[i][0], acc[i][1], acc[i][2], acc[i][3]);
        *(float4*)(C + (size_t)((ty << 2) + i) * ldc + (tx << 2)) = w;
    }
}

// grid.x = N/64 tiles, grid.y = K-split; writes C + y*partStride (partStride=0 when no split)
__global__ __launch_bounds__(256) void k_gemm_bt(const float* __restrict__ A, int lda,
                                                 const float* __restrict__ B, int ldb,
                                                 float* __restrict__ C, long long ldc,
                                                 int KC, long long partStride)
{
    int n0 = blockIdx.x << 6;
    int k0 = blockIdx.y * KC;
    gemm_tile<true>(A + k0, lda, B + (size_t)n0 * ldb + k0, ldb,
                    C + (size_t)blockIdx.y * partStride + n0, (size_t)ldc, KC);
}

__global__ __launch_bounds__(256) void k_gemm_bn(const float* __restrict__ A, int lda,
                                                 const float* __restrict__ B, int ldb,
                                                 float* __restrict__ C, long long ldc,
                                                 int KC, long long partStride)
{
    int n0 = blockIdx.x << 6;
    int k0 = blockIdx.y * KC;
    gemm_tile<false>(A + k0, lda, B + (size_t)k0 * ldb + n0, ldb,
                     C + (size_t)blockIdx.y * partStride + n0, (size_t)ldc, KC);
}

// gates = prev @ W_ih^T + h @ W_hh^T  (split over 3 K-chunks of 512 via grid.y)
__global__ __launch_bounds__(256) void k_gates(const float* __restrict__ prev,
                                               const float* __restrict__ h,
                                               const float* __restrict__ Wih,
                                               const float* __restrict__ Whh,
                                               float* __restrict__ part)
{
    int n0 = blockIdx.x << 6;
    int ks = blockIdx.y;
    const float* A; const float* Bp; int lda, ldb;
    if (ks == 0) { A = prev;                lda = EMBD; Bp = Wih + (size_t)n0 * EMBD;                  ldb = EMBD; }
    else         { A = h + (ks - 1) * 512;  lda = HH;   Bp = Whh + (size_t)n0 * HH + (ks - 1) * 512;   ldb = HH;   }
    gemm_tile<true>(A, lda, Bp, ldb, part + (size_t)ks * BB * 4096 + n0, 4096, 512);
}

// reduce 3 gate partials + bias, LSTM cell update; writes h, c, and h-half of hc
__global__ void k_lstm(const float* __restrict__ part, const float* __restrict__ bias,
                       float* __restrict__ h, float* __restrict__ c, float* __restrict__ hc)
{
    int idx = blockIdx.x * 256 + threadIdx.x;     // 65536 = 64 x 1024
    int b = idx >> 10, j = idx & 1023;
    size_t base = (size_t)b * 4096;
    #define GATE(col) (part[base + (col)] + part[base + (col) + 262144] + part[base + (col) + 524288] + bias[(col)])
    float gi = GATE(j);
    float gf = GATE(j + 1024);
    float gg = GATE(j + 2048);
    float go = GATE(j + 3072);
    #undef GATE
    float si = 1.f / (1.f + expf(-gi));
    float sf = 1.f / (1.f + expf(-gf));
    float so = 1.f / (1.f + expf(-go));
    float cn = sf * c[idx] + si * tanhf(gg);
    float hn = so * tanhf(cn);
    c[idx] = cn;
    h[idx] = hn;
    hc[(size_t)b * 2048 + j] = hn;
}

// per-b attention: reduce q partials, scores = enc . q, masked softmax, c_t = alpha . enc
__global__ __launch_bounds__(256) void k_attn(const float* __restrict__ qpart,
                                              const float* __restrict__ enc,
                                              const int* __restrict__ enc_len,
                                              float* __restrict__ hc)
{
    __shared__ float qs[1024];
    __shared__ float sc[128];
    int b = blockIdx.x, tid = threadIdx.x;
    for (int e = tid; e < 1024; e += 256) {
        size_t o = (size_t)b * 1024 + e;
        qs[e] = qpart[o] + qpart[o + 65536] + qpart[o + 131072] + qpart[o + 196608];
    }
    __syncthreads();
    int lane = tid & 63, w = tid >> 6;
    const float* eb = enc + (size_t)b * SS * EE;
    for (int s = w; s < 128; s += 4) {
        const float* er = eb + (size_t)s * 1024;
        float acc = 0.f;
        #pragma unroll
        for (int i = 0; i < 16; ++i) acc = fmaf(er[i * 64 + lane], qs[i * 64 + lane], acc);
        #pragma unroll
        for (int off = 32; off; off >>= 1) acc += __shfl_xor(acc, off, 64);
        if (lane == 0) sc[s] = acc;
    }
    __syncthreads();
    int len = enc_len[b];
    if (tid < 64) {
        float a  = (tid < len)      ? sc[tid]      : -1e9f;
        float a2 = (tid + 64 < len) ? sc[tid + 64] : -1e9f;
        float m = fmaxf(a, a2);
        #pragma unroll
        for (int off = 32; off; off >>= 1) m = fmaxf(m, __shfl_xor(m, off, 64));
        float ea = expf(a - m), ea2 = expf(a2 - m);
        float ssum = ea + ea2;
        #pragma unroll
        for (int off = 32; off; off >>= 1) ssum += __shfl_xor(ssum, off, 64);
        sc[tid] = ea / ssum; sc[tid + 64] = ea2 / ssum;
    }
    __syncthreads();
    float acc[4] = {0.f, 0.f, 0.f, 0.f};
    for (int s = 0; s < 128; ++s) {
        float al = sc[s];
        const float* er = eb + (size_t)s * 1024;
        #pragma unroll
        for (int j = 0; j < 4; ++j) acc[j] = fmaf(al, er[tid + j * 256], acc[j]);
    }
    #pragma unroll
    for (int j = 0; j < 4; ++j) hc[(size_t)b * 2048 + 1024 + tid + j * 256] = acc[j];
}

__global__ void k_reduce_dec(const float* __restrict__ part, float* __restrict__ dec)
{
    int i = blockIdx.x * 256 + threadIdx.x;   // 32768
    float s = 0.f;
    #pragma unroll
    for (int p = 0; p < 8; ++p) s += part[p * 32768 + i];
    dec[i] = s;
}

// per-b argmax over logits row (lowest index wins ties), set prev embedding + tl
__global__ __launch_bounds__(256) void k_argmax(const float* __restrict__ out,
                                                const float* __restrict__ emb,
                                                float* __restrict__ prev,
                                                int* __restrict__ sym, int* __restrict__ tl, int t)
{
    __shared__ float bv[256];
    __shared__ int   bi[256];
    int b = blockIdx.x, tid = threadIdx.x;
    const float* row = out + (size_t)b * TT * VV + (size_t)t * VV;
    float mv = -INFINITY; int mi = 0;
    for (int v = tid; v < VV; v += 256) {
        float x = row[v];
        if (x > mv) { mv = x; mi = v; }
    }
    bv[tid] = mv; bi[tid] = mi;
    __syncthreads();
    for (int s = 128; s; s >>= 1) {
        if (tid < s) {
            float ov = bv[tid + s]; int oi = bi[tid + s];
            if (ov > bv[tid] || (ov == bv[tid] && oi < bi[tid])) { bv[tid] = ov; bi[tid] = oi; }
        }
        __syncthreads();
    }
    int best = bi[0];
    if (tid == 0) { sym[b] = best; if (best == 1) tl[b] = t + 1; }
    for (int e = tid; e < EMBD; e += 256)
        prev[(size_t)b * EMBD + e] = emb[(size_t)best * EMBD + e];
}

__global__ void k_tl(const int* __restrict__ sym, const int* __restrict__ tl, float* __restrict__ out_tl)
{
    int b = threadIdx.x;
    out_tl[b] = (float)((sym[b] == 1) ? tl[b] : TT);
}

// in-place log_softmax per (b,t) row of 32000
__global__ __launch_bounds__(256) void k_logsm(float* __restrict__ out)
{
    __shared__ float red[256];
    size_t base = (size_t)blockIdx.x * VV;
    int tid = threadIdx.x;
    float lm = -INFINITY;
    for (int v = tid; v < VV; v += 256) lm = fmaxf(lm, out[base + v]);
    red[tid] = lm; __syncthreads();
    for (int s = 128; s; s >>= 1) { if (tid < s) red[tid] = fmaxf(red[tid], red[tid + s]); __syncthreads(); }
    float mx = red[0];
    __syncthreads();
    float ls = 0.f;
    for (int v = tid; v < VV; v += 256) ls += expf(out[base + v] - mx);
    red[tid] = ls; __syncthreads();
    for (int s = 128; s; s >>= 1) { if (tid < s) red[tid] += red[tid + s]; __syncthreads(); }
    float lse = mx + logf(red[0]);
    for (int v = tid; v < VV; v += 256) out[base + v] -= lse;
}

__global__ void k_init(const float* __restrict__ dis, float* __restrict__ h, float* __restrict__ c,
                       float* __restrict__ prev, int* __restrict__ tl)
{
    int idx = blockIdx.x * 256 + threadIdx.x;   // 65536
    h[idx] = dis[idx];            // dec_initial_state[0,0,:,:]
    c[idx] = dis[65536 + idx];    // dec_initial_state[1,0,:,:]
    if (idx < 32768) prev[idx] = 0.f;
    if (idx < 64) tl[idx] = 0;
}

extern "C" void kernel_launch(void* const* d_in, const int* in_sizes, int n_in,
                              void* d_out, int out_size, void* d_ws, size_t ws_size,
                              hipStream_t stream)
{
    const float* dis  = (const float*)d_in[0];   // [2,1,64,1024]
    const float* enc  = (const float*)d_in[1];   // [64,128,1024]
    const int*   elen = (const int*)  d_in[2];   // [64]
    const float* Wih  = (const float*)d_in[4];   // [4096,512]
    const float* Whh  = (const float*)d_in[5];   // [4096,1024]
    const float* bl   = (const float*)d_in[6];   // [4096]
    const float* Wap  = (const float*)d_in[7];   // [1024,1024]  (H x E)
    const float* Wout = (const float*)d_in[8];   // [512,2048]
    const float* Wvoc = (const float*)d_in[9];   // [32000,512]
    const float* emb  = (const float*)d_in[10];  // [32000,512]
    float* out = (float*)d_out;
    float* ws  = (float*)d_ws;

    // workspace layout (floats)
    float* h     = ws;                 // 64x1024
    float* c     = h     + 65536;      // 64x1024
    float* prev  = c     + 65536;      // 64x512
    float* hc    = prev  + 32768;      // 64x2048  = [h | c_t]
    float* qpart = hc    + 131072;     // 4 x 64x1024
    float* gpart = qpart + 262144;     // 3 x 64x4096
    float* dpart = gpart + 786432;     // 8 x 64x512
    float* dec   = dpart + 262144;     // 64x512
    int*   sym   = (int*)(dec + 32768);
    int*   tl    = sym + 64;

    k_init<<<256, 256, 0, stream>>>(dis, h, c, prev, tl);

    for (int t = 0; t < TT; ++t) {
        // LSTM gates: prev@Wih^T + h@Whh^T (3-way K split)
        k_gates<<<dim3(64, 3), 256, 0, stream>>>(prev, h, Wih, Whh, gpart);
        k_lstm<<<256, 256, 0, stream>>>(gpart, bl, h, c, hc);
        // q = h @ W_attproj  (B is [K=H, N=E]); 4-way K split
        k_gemm_bn<<<dim3(16, 4), 256, 0, stream>>>(h, HH, Wap, EE, qpart, EE, 256, 65536);
        // attention per b: reduce q, scores, softmax, c_t -> hc[:,1024:]
        k_attn<<<64, 256, 0, stream>>>(qpart, enc, elen, hc);
        // dec = hc @ W_out^T ; 8-way K split over K=2048
        k_gemm_bt<<<dim3(8, 8), 256, 0, stream>>>(hc, 2048, Wout, 2048, dpart, 512, 256, 32768);
        k_reduce_dec<<<128, 256, 0, stream>>>(dpart, dec);
        // vocab logits straight into d_out[b, t, :]
        k_gemm_bt<<<dim3(500, 1), 256, 0, stream>>>(dec, 512, Wvoc, 512,
                                                    out + (size_t)t * VV, (long long)TT * VV, 512, 0);
        // greedy symbol + embedding feedback
        k_argmax<<<64, 256, 0, stream>>>(out, emb, prev, sym, tl, t);
    }

    k_tl<<<1, 64, 0, stream>>>(sym, tl, out + (size_t)BB * TT * VV);
    k_logsm<<<3200, 256, 0, stream>>>(out);
}